// Round 1
// 21844.182 us; speedup vs baseline: 1.5781x; 1.5781x over previous
//
#include <hip/hip_runtime.h>
#include <cstdint>
#include <cstddef>

#define B_ 8
#define C_ 256
#define H_ 160
#define W_ 160
#define HW_ 25600
#define P_ 204800          // B*H*W
#define BH_ 1280           // B*H
#define SIMG 52428800      // B*C*H*W floats
#define SSCORE 32768000    // B*H*W*W floats

__device__ __forceinline__ float4 ld4(const float* p) { return *(const float4*)p; }
__device__ __forceinline__ void st4(float* p, float4 v) { *(float4*)p = v; }
__device__ __forceinline__ float silu(float v) { return v / (1.f + __expf(-v)); }

// ---------------- weight transposes (run once per launch, trivial) -------------
__global__ __launch_bounds__(256) void transpose_rbw_kernel(const float* __restrict__ w,
                                                            float* __restrict__ wT) {
  int idx = blockIdx.x * 256 + threadIdx.x;          // total 256*256*9
  if (idx >= 256 * 256 * 9) return;
  int tap = idx % 9;
  int ci  = (idx / 9) & 255;
  int co  = idx / 2304;
  wT[(ci * 9 + tap) * 256 + co] = w[idx];
}

__global__ __launch_bounds__(256) void transpose_mat_kernel(const float* __restrict__ w,
                                                            float* __restrict__ wT, int K) {
  int idx = blockIdx.x * 256 + threadIdx.x;          // total 256*K, layout (o,K)->(K,256)
  if (idx >= 256 * K) return;
  int k = idx % K;
  int o = idx / K;
  wT[k * 256 + o] = w[idx];
}

// ---------------- 3x3 conv, SAME, C=256->256, optional SiLU or skip-add --------
// out tile: 2 rows x 32 cols x 64 co per block; 256 threads, 4co x 4x each.
__global__ __launch_bounds__(256) void conv3x3_kernel(const float* __restrict__ in,
                                                      const float* __restrict__ wT,
                                                      const float* __restrict__ skip,
                                                      float* __restrict__ out, int mode) {
  __shared__ __align__(16) float sIn[16 * 4 * 40];   // [ci][y0..3][x0..39], valid x<34
  __shared__ __align__(16) float sW[16 * 9 * 64];    // [ci][tap][co]
  int bx = blockIdx.x;
  int xt = bx % 5;
  int yt = (bx / 5) % 80;
  int ot = (bx / 400) % 4;
  int b  = bx / 1600;
  int x0 = xt * 32, y0 = yt * 2, o0 = ot * 64;
  int tid = threadIdx.x;
  int tc = tid & 15, tp = tid >> 4;
  int ty = tp & 1, xq = tp >> 1;
  int xt4 = xq * 4;
  float acc[4][4] = {};                              // [co][x]
  const float* inB = in + (size_t)b * C_ * HW_;
  for (int cb = 0; cb < 256; cb += 16) {
    for (int r = tid; r < 16 * 4 * 40; r += 256) {
      int xl = r % 40;
      int yl = (r / 40) & 3;
      int cl = r / 160;
      float v = 0.f;
      int gx = x0 + xl - 1, gy = y0 + yl - 1;
      if (xl < 34 && gx >= 0 && gx < W_ && gy >= 0 && gy < H_)
        v = inB[(size_t)(cb + cl) * HW_ + gy * W_ + gx];
      sIn[r] = v;
    }
    for (int r = tid; r < 16 * 9 * 64; r += 256) {
      int col = r & 63;
      int tap = (r >> 6) % 9;
      int cl  = r / 576;
      sW[r] = wT[((cb + cl) * 9 + tap) * 256 + o0 + col];
    }
    __syncthreads();
    for (int ci = 0; ci < 16; ci++) {
      float rv[3][6];
#pragma unroll
      for (int dy = 0; dy < 3; dy++) {
        const float* rb = &sIn[ci * 160 + (ty + dy) * 40 + xt4];
        float4 a = ld4(rb);
        rv[dy][0] = a.x; rv[dy][1] = a.y; rv[dy][2] = a.z; rv[dy][3] = a.w;
        rv[dy][4] = rb[4]; rv[dy][5] = rb[5];
      }
#pragma unroll
      for (int dy = 0; dy < 3; dy++) {
#pragma unroll
        for (int dx = 0; dx < 3; dx++) {
          float4 w4 = ld4(&sW[(ci * 9 + dy * 3 + dx) * 64 + tc * 4]);
#pragma unroll
          for (int xi = 0; xi < 4; xi++) {
            float v = rv[dy][xi + dx];
            acc[0][xi] = fmaf(w4.x, v, acc[0][xi]);
            acc[1][xi] = fmaf(w4.y, v, acc[1][xi]);
            acc[2][xi] = fmaf(w4.z, v, acc[2][xi]);
            acc[3][xi] = fmaf(w4.w, v, acc[3][xi]);
          }
        }
      }
    }
    __syncthreads();
  }
  int gy = y0 + ty, gx = x0 + xt4;
  for (int o = 0; o < 4; o++) {
    int oc = o0 + tc * 4 + o;
    size_t base = ((size_t)b * C_ + oc) * HW_ + (size_t)gy * W_ + gx;
    float4 r;
    if (mode == 0) {
      r.x = silu(acc[o][0]); r.y = silu(acc[o][1]); r.z = silu(acc[o][2]); r.w = silu(acc[o][3]);
    } else {
      float4 sk = ld4(&skip[base]);
      r.x = acc[o][0] + sk.x; r.y = acc[o][1] + sk.y; r.z = acc[o][2] + sk.z; r.w = acc[o][3] + sk.w;
    }
    st4(&out[base], r);
  }
}

// ---------------- 1x1 conv: channel-major in -> pixel-major out ----------------
__global__ __launch_bounds__(256) void conv1x1_kernel(const float* __restrict__ in,
                                                      const float* __restrict__ wTc,
                                                      const float* __restrict__ bias,
                                                      float* __restrict__ out) {
  __shared__ __align__(16) float sA[16 * 68];        // [c][p]
  __shared__ __align__(16) float sW[16 * 68];        // [c][o]
  int bx = blockIdx.x;
  int pt = bx % 3200;
  int ot = bx / 3200;
  int p0 = pt * 64, o0 = ot * 64;
  int b = p0 / HW_;
  size_t inOff = (size_t)b * C_ * HW_ + (p0 % HW_);
  int tid = threadIdx.x;
  int tc = tid & 15, tp = tid >> 4;
  float acc[4][4] = {};                              // [pp][oo]
  for (int cb = 0; cb < 256; cb += 16) {
    for (int r = tid; r < 1024; r += 256) {
      int pl = r & 63, cl = r >> 6;
      sA[cl * 68 + pl] = in[inOff + (size_t)(cb + cl) * HW_ + pl];
    }
    for (int r = tid; r < 1024; r += 256) {
      int ol = r & 63, cl = r >> 6;
      sW[cl * 68 + ol] = wTc[(cb + cl) * 256 + o0 + ol];
    }
    __syncthreads();
#pragma unroll
    for (int c = 0; c < 16; c++) {
      float4 a4 = ld4(&sA[c * 68 + tp * 4]);
      float4 w4 = ld4(&sW[c * 68 + tc * 4]);
      float av[4] = {a4.x, a4.y, a4.z, a4.w};
      float wv[4] = {w4.x, w4.y, w4.z, w4.w};
#pragma unroll
      for (int pp = 0; pp < 4; pp++)
#pragma unroll
        for (int oo = 0; oo < 4; oo++) acc[pp][oo] = fmaf(av[pp], wv[oo], acc[pp][oo]);
    }
    __syncthreads();
  }
  float4 bi = ld4(&bias[o0 + tc * 4]);
  float bb[4] = {bi.x, bi.y, bi.z, bi.w};
  for (int pp = 0; pp < 4; pp++) {
    float4 r = {acc[pp][0] + bb[0], acc[pp][1] + bb[1], acc[pp][2] + bb[2], acc[pp][3] + bb[3]};
    st4(&out[(size_t)(p0 + tp * 4 + pp) * 256 + o0 + tc * 4], r);
  }
}

// ---------------- score[i,j] = sum_c Q[i,c]*S[j,c], per (b,h) ------------------
__global__ __launch_bounds__(256) void score_kernel(const float* __restrict__ Q,
                                                    const float* __restrict__ S,
                                                    float* __restrict__ score) {
  __shared__ __align__(16) float sQ[16 * 68];        // [c][i]
  __shared__ __align__(16) float sS[16 * 68];        // [c][j]
  int bx = blockIdx.x;
  int bh = bx / 9;
  int tt = bx % 9;
  int it = tt / 3, jt = tt % 3;
  int i0 = it * 64, j0 = jt * 64;
  int tid = threadIdx.x;
  int tj = tid & 15, ti = tid >> 4;
  float acc[4][4] = {};                              // [ii][jj]
  const float* Qb = Q + (size_t)bh * W_ * 256;
  const float* Sb = S + (size_t)bh * W_ * 256;
  for (int cb = 0; cb < 256; cb += 16) {
    for (int r = tid; r < 1024; r += 256) {
      int cl = r & 15, il = r >> 4;
      int gi = i0 + il;
      sQ[cl * 68 + il] = (gi < W_) ? Qb[(size_t)gi * 256 + cb + cl] : 0.f;
    }
    for (int r = tid; r < 1024; r += 256) {
      int cl = r & 15, jl = r >> 4;
      int gj = j0 + jl;
      sS[cl * 68 + jl] = (gj < W_) ? Sb[(size_t)gj * 256 + cb + cl] : 0.f;
    }
    __syncthreads();
#pragma unroll
    for (int c = 0; c < 16; c++) {
      float4 q4 = ld4(&sQ[c * 68 + ti * 4]);
      float4 s4 = ld4(&sS[c * 68 + tj * 4]);
      float qv[4] = {q4.x, q4.y, q4.z, q4.w};
      float sv[4] = {s4.x, s4.y, s4.z, s4.w};
#pragma unroll
      for (int ii = 0; ii < 4; ii++)
#pragma unroll
        for (int jj = 0; jj < 4; jj++) acc[ii][jj] = fmaf(qv[ii], sv[jj], acc[ii][jj]);
    }
    __syncthreads();
  }
  if (j0 + tj * 4 < W_) {
    for (int ii = 0; ii < 4; ii++) {
      int gi = i0 + ti * 4 + ii;
      if (gi < W_) {
        float4 r = {acc[ii][0], acc[ii][1], acc[ii][2], acc[ii][3]};
        st4(&score[(size_t)bh * HW_ + (size_t)gi * W_ + j0 + tj * 4], r);
      }
    }
  }
}

// ---------------- per-(b,h) row & column softmax stats -------------------------
__global__ __launch_bounds__(256) void stats_kernel(const float* __restrict__ score,
                                                    float* __restrict__ rmax, float* __restrict__ rsinv,
                                                    float* __restrict__ cmax, float* __restrict__ csinv) {
  int bh = blockIdx.x;
  const float* sc = score + (size_t)bh * HW_;
  int tid = threadIdx.x;
  int lane = tid & 63, wv = tid >> 6;
  const float NEG = -3.0e38f;
  for (int r = wv; r < W_; r += 4) {
    float v0 = sc[r * W_ + lane];
    float v1 = sc[r * W_ + 64 + lane];
    float v2 = (lane < 32) ? sc[r * W_ + 128 + lane] : NEG;
    float m = fmaxf(fmaxf(v0, v1), v2);
#pragma unroll
    for (int off = 32; off > 0; off >>= 1) m = fmaxf(m, __shfl_xor(m, off));
    float s = __expf(v0 - m) + __expf(v1 - m) + ((lane < 32) ? __expf(v2 - m) : 0.f);
#pragma unroll
    for (int off = 32; off > 0; off >>= 1) s += __shfl_xor(s, off);
    if (lane == 0) { rmax[bh * W_ + r] = m; rsinv[bh * W_ + r] = 1.f / s; }
  }
  for (int c = wv; c < W_; c += 4) {
    float v0 = sc[lane * W_ + c];
    float v1 = sc[(64 + lane) * W_ + c];
    float v2 = (lane < 32) ? sc[(128 + lane) * W_ + c] : NEG;
    float m = fmaxf(fmaxf(v0, v1), v2);
#pragma unroll
    for (int off = 32; off > 0; off >>= 1) m = fmaxf(m, __shfl_xor(m, off));
    float s = __expf(v0 - m) + __expf(v1 - m) + ((lane < 32) ? __expf(v2 - m) : 0.f);
#pragma unroll
    for (int off = 32; off > 0; off >>= 1) s += __shfl_xor(s, off);
    if (lane == 0) { cmax[bh * W_ + c] = m; csinv[bh * W_ + c] = 1.f / s; }
  }
}

// ---- write M_r2l in-place over score, M_l2r transposed; accumulate colsums ----
__global__ __launch_bounds__(256) void smwrite_kernel(float* __restrict__ scoreM,
                                                      float* __restrict__ Ml2r,
                                                      const float* __restrict__ rmax, const float* __restrict__ rsinv,
                                                      const float* __restrict__ cmax, const float* __restrict__ csinv,
                                                      float* __restrict__ cs_l2r, float* __restrict__ cs_r2l) {
  __shared__ __align__(16) float sT[64 * 65];
  int bx = blockIdx.x;
  int bh = bx / 9;
  int tt = bx % 9;
  int i0 = (tt / 3) * 64, j0 = (tt % 3) * 64;
  int tid = threadIdx.x;
  int jl = tid & 63, g = tid >> 6;
  int gj = j0 + jl;
  bool jv = gj < W_;
  float cm = 0.f, cv = 0.f;
  if (jv) { cm = cmax[bh * W_ + gj]; cv = csinv[bh * W_ + gj]; }
  float pcs = 0.f;
  for (int k = 0; k < 16; k++) {
    int il = g + 4 * k;
    int gi = i0 + il;
    float ml = 0.f;
    if (gi < W_ && jv) {
      size_t ad = (size_t)bh * HW_ + (size_t)gi * W_ + gj;
      float s = scoreM[ad];
      float mr = __expf(s - rmax[bh * W_ + gi]) * rsinv[bh * W_ + gi];
      scoreM[ad] = mr;
      pcs += mr;
      ml = __expf(s - cm) * cv;
    }
    sT[il * 65 + jl] = ml;
  }
  if (jv) atomicAdd(&cs_r2l[bh * W_ + gj], pcs);
  __syncthreads();
  int il2 = tid & 63;
  int gi2 = i0 + il2;
  bool iv = gi2 < W_;
  float pls = 0.f;
  for (int k = 0; k < 16; k++) {
    int jl2 = g + 4 * k;
    int gj2 = j0 + jl2;
    float v = sT[il2 * 65 + jl2];
    if (gj2 < W_ && iv) {
      Ml2r[(size_t)bh * HW_ + (size_t)gj2 * W_ + gi2] = v;
      pls += v;
    }
  }
  if (iv) atomicAdd(&cs_l2r[bh * W_ + gi2], pls);
}

// ---------------- morphology: union-find CCL + disk(3) closing -----------------
// find root (min-index); volatile reads so LDS updates by other lanes are seen
__device__ __forceinline__ int uf_find(volatile int* lab, int p) {
  int q = lab[p];
  while (q != p) { p = q; q = lab[p]; }
  return p;
}

__device__ __forceinline__ void uf_union(volatile int* lab, int a, int b) {
  while (true) {
    a = uf_find(lab, a);
    b = uf_find(lab, b);
    if (a == b) return;
    int hi = a > b ? a : b;
    int lo = a ^ b ^ hi;
    int old = atomicMin((int*)&lab[hi], lo);
    if (old == hi) return;                           // linked hi -> lo
    a = lo; b = old;                                 // hi already had parent 'old'
  }
}

__device__ __forceinline__ bool getbit(const unsigned int* bits, int p) {
  return (bits[p >> 5] >> (p & 31)) & 1u;
}

__global__ __launch_bounds__(1024) void morph_kernel(const float* __restrict__ colsum,
                                                     float* __restrict__ Vout,
                                                     unsigned int* __restrict__ cnt) {
  __shared__ int lab[25600];                         // 100 KB: parent pointers
  __shared__ unsigned int mbits[800];                // current mask bitset
  __shared__ unsigned int dbits[862];                // scratch / dilated bitset
  volatile int* vlab = lab;
  const int tid = threadIdx.x;
  const int blk = blockIdx.x;                        // dir*8 + b
  const float* cs = colsum + (size_t)blk * HW_;
  float* vo = Vout + (size_t)blk * HW_;
  unsigned int* cn = cnt + (size_t)blk * HW_;
  volatile unsigned int* vcn = cn;

  for (int i = tid; i < HW_; i += 1024) cn[i] = 0u;
  for (int i = tid; i < 800; i += 1024) mbits[i] = 0u;
  __syncthreads();
  for (int p = tid; p < HW_; p += 1024) {
    lab[p] = p;
    if (cs[p] <= 0.1f) atomicOr(&mbits[p >> 5], 1u << (p & 31));   // m = ~V
  }
  __syncthreads();

  // ---- stage 1: CC of mask (8-connectivity), single merge pass ----
  for (int p = tid; p < HW_; p += 1024) {
    if (!getbit(mbits, p)) continue;
    int y = p / 160, x = p - y * 160;
    if (x > 0 && getbit(mbits, p - 1)) uf_union(vlab, p, p - 1);
    if (y > 0) {
      int q = p - 160;
      if (getbit(mbits, q)) uf_union(vlab, p, q);
      if (x > 0 && getbit(mbits, q - 1)) uf_union(vlab, p, q - 1);
      if (x < 159 && getbit(mbits, q + 1)) uf_union(vlab, p, q + 1);
    }
  }
  __syncthreads();
  for (int p = tid; p < HW_; p += 1024) lab[p] = uf_find(vlab, p);  // compress
  __syncthreads();
  for (int p = tid; p < HW_; p += 1024)
    if (getbit(mbits, p)) atomicAdd(&cn[lab[p]], 1u);
  for (int i = tid; i < 862; i += 1024) dbits[i] = 0u;
  __syncthreads();
  // m1 = mask & size>=20  -> dbits (scratch)
  for (int p = tid; p < HW_; p += 1024) {
    if (getbit(mbits, p) && vcn[lab[p]] >= 20u)
      atomicOr(&dbits[p >> 5], 1u << (p & 31));
  }
  __syncthreads();
  // ---- stage 2 init: mask = ~m1; mbits <- m1; cn <- 0; lab <- p ----
  for (int i = tid; i < 800; i += 1024) mbits[i] = dbits[i];
  for (int i = tid; i < HW_; i += 1024) cn[i] = 0u;
  for (int p = tid; p < HW_; p += 1024) lab[p] = p;
  __syncthreads();
  // ---- stage 2: CC of background (~m1), single merge pass ----
  for (int p = tid; p < HW_; p += 1024) {
    if (getbit(mbits, p)) continue;                  // skip m1 pixels
    int y = p / 160, x = p - y * 160;
    if (x > 0 && !getbit(mbits, p - 1)) uf_union(vlab, p, p - 1);
    if (y > 0) {
      int q = p - 160;
      if (!getbit(mbits, q)) uf_union(vlab, p, q);
      if (x > 0 && !getbit(mbits, q - 1)) uf_union(vlab, p, q - 1);
      if (x < 159 && !getbit(mbits, q + 1)) uf_union(vlab, p, q + 1);
    }
  }
  __syncthreads();
  for (int p = tid; p < HW_; p += 1024) lab[p] = uf_find(vlab, p);  // compress
  __syncthreads();
  for (int p = tid; p < HW_; p += 1024)
    if (!getbit(mbits, p)) atomicAdd(&cn[lab[p]], 1u);
  __syncthreads();
  // m2 = m1 | (bg & size<=10): OR the filled holes into mbits
  for (int p = tid; p < HW_; p += 1024) {
    if (!getbit(mbits, p) && vcn[lab[p]] <= 10u)
      atomicOr(&mbits[p >> 5], 1u << (p & 31));      // each p sets only its own bit
  }
  __syncthreads();

  // ---- closing: dilation on 166x166 zero-padded domain, then erosion ----
  const int HWD[7] = {0, 2, 2, 3, 2, 2, 0};
  for (int w = tid; w < 862; w += 1024) {
    unsigned int word = 0u;
    for (int bit = 0; bit < 32; bit++) {
      int q = w * 32 + bit;
      if (q >= 27556) break;
      int py = q / 166, px = q - py * 166;
      bool v = false;
      for (int dy = -3; dy <= 3 && !v; dy++) {
        int oy = py + dy - 3;
        if (oy < 0 || oy >= 160) continue;
        int hw = HWD[dy + 3];
        for (int dx = -hw; dx <= hw; dx++) {
          int ox = px + dx - 3;
          if (ox < 0 || ox >= 160) continue;
          int idx = oy * 160 + ox;
          if ((mbits[idx >> 5] >> (idx & 31)) & 1u) { v = true; break; }
        }
      }
      if (v) word |= (1u << bit);
    }
    dbits[w] = word;
  }
  __syncthreads();
  // erosion (full disk must be set), crop, invert -> float
  for (int p = tid; p < HW_; p += 1024) {
    int y = p / 160, x = p - y * 160;
    bool all = true;
    for (int dy = -3; dy <= 3 && all; dy++) {
      int qy = y + 3 + dy;
      int hw = HWD[dy + 3];
      for (int dx = -hw; dx <= hw; dx++) {
        int q = qy * 166 + (x + 3 + dx);
        if (!((dbits[q >> 5] >> (q & 31)) & 1u)) { all = false; break; }
      }
    }
    vo[p] = all ? 0.0f : 1.0f;
  }
}

// ---------------- buf = M (160x160) @ X (160x256), X channel-major -------------
__global__ __launch_bounds__(256) void buf_kernel(const float* __restrict__ M,
                                                  const float* __restrict__ X,
                                                  float* __restrict__ outBuf) {
  __shared__ __align__(16) float sM[16 * 68];        // [j][i]
  __shared__ __align__(16) float sX[16 * 68];        // [j][c]
  int bx = blockIdx.x;
  int bh = bx / 12;
  int tt = bx % 12;
  int it = tt / 4, ct = tt % 4;
  int i0 = it * 64, c0 = ct * 64;
  int b = bh / H_, h = bh % H_;
  int tid = threadIdx.x;
  int tc = tid & 15, ti = tid >> 4;
  float acc[4][4] = {};                              // [ii][cc]
  const float* Mb = M + (size_t)bh * HW_;
  const float* Xb = X + (size_t)b * C_ * HW_ + (size_t)h * W_;
  for (int jb = 0; jb < W_; jb += 16) {
    for (int r = tid; r < 1024; r += 256) {
      int jl = r & 15, il = r >> 4;
      int gi = i0 + il;
      sM[jl * 68 + il] = (gi < W_) ? Mb[(size_t)gi * W_ + jb + jl] : 0.f;
    }
    for (int r = tid; r < 1024; r += 256) {
      int jl = r & 15, cl = r >> 4;
      sX[jl * 68 + cl] = Xb[(size_t)(c0 + cl) * HW_ + jb + jl];
    }
    __syncthreads();
#pragma unroll
    for (int j = 0; j < 16; j++) {
      float4 m4 = ld4(&sM[j * 68 + ti * 4]);
      float4 x4 = ld4(&sX[j * 68 + tc * 4]);
      float mm[4] = {m4.x, m4.y, m4.z, m4.w};
      float xx[4] = {x4.x, x4.y, x4.z, x4.w};
#pragma unroll
      for (int ii = 0; ii < 4; ii++)
#pragma unroll
        for (int cc = 0; cc < 4; cc++) acc[ii][cc] = fmaf(mm[ii], xx[cc], acc[ii][cc]);
    }
    __syncthreads();
  }
  for (int ii = 0; ii < 4; ii++) {
    int gi = i0 + ti * 4 + ii;
    if (gi < W_) {
      float4 r = {acc[ii][0], acc[ii][1], acc[ii][2], acc[ii][3]};
      st4(&outBuf[((size_t)bh * W_ + gi) * 256 + c0 + tc * 4], r);
    }
  }
}

// -------- out = bn_w[:, :256]@buf + bn_w[:,256:512]@x + bn_w[:,512]*V + b ------
__global__ __launch_bounds__(256) void final_kernel(const float* __restrict__ buf,
                                                    const float* __restrict__ x,
                                                    const float* __restrict__ V,
                                                    const float* __restrict__ bnT,
                                                    const float* __restrict__ bnb,
                                                    float* __restrict__ out, int side) {
  __shared__ __align__(16) float sA[16 * 68];        // [k][p]
  __shared__ __align__(16) float sW[16 * 68];        // [k][o]
  int bx = blockIdx.x;
  int pt = bx % 3200;
  int ot = bx / 3200;
  int p0 = pt * 64, o0 = ot * 64;
  int b = p0 / HW_;
  int p2 = p0 % HW_;
  int tid = threadIdx.x;
  int tc = tid & 15, tp = tid >> 4;
  float acc[4][4] = {};                              // [pp][oo]
  for (int kb = 0; kb < 32; kb++) {
    if (kb < 16) {
      for (int r = tid; r < 1024; r += 256) {
        int kl = r & 15, pl = r >> 4;
        sA[kl * 68 + pl] = buf[(size_t)(p0 + pl) * 256 + kb * 16 + kl];
      }
    } else {
      for (int r = tid; r < 1024; r += 256) {
        int pl = r & 63, kl = r >> 6;
        sA[kl * 68 + pl] = x[((size_t)b * C_ + (kb - 16) * 16 + kl) * HW_ + p2 + pl];
      }
    }
    for (int r = tid; r < 1024; r += 256) {
      int ol = r & 63, kl = r >> 6;
      sW[kl * 68 + ol] = bnT[(size_t)(kb * 16 + kl) * 256 + o0 + ol];
    }
    __syncthreads();
#pragma unroll
    for (int k = 0; k < 16; k++) {
      float4 a4 = ld4(&sA[k * 68 + tp * 4]);
      float4 w4 = ld4(&sW[k * 68 + tc * 4]);
      float av[4] = {a4.x, a4.y, a4.z, a4.w};
      float wv[4] = {w4.x, w4.y, w4.z, w4.w};
#pragma unroll
      for (int pp = 0; pp < 4; pp++)
#pragma unroll
        for (int oo = 0; oo < 4; oo++) acc[pp][oo] = fmaf(av[pp], wv[oo], acc[pp][oo]);
    }
    __syncthreads();
  }
  float4 wv4 = ld4(&bnT[(size_t)512 * 256 + o0 + tc * 4]);
  float wv[4] = {wv4.x, wv4.y, wv4.z, wv4.w};
  float4 bi4 = ld4(&bnb[o0 + tc * 4]);
  float bb[4] = {bi4.x, bi4.y, bi4.z, bi4.w};
  float vv[4];
  for (int pp = 0; pp < 4; pp++) vv[pp] = V[p0 + tp * 4 + pp];
#pragma unroll
  for (int pp = 0; pp < 4; pp++)
#pragma unroll
    for (int oo = 0; oo < 4; oo++) acc[pp][oo] = fmaf(wv[oo], vv[pp], acc[pp][oo]);
  size_t outBase = ((size_t)b * 512 + side * 256) * HW_ + p2;
  for (int oo = 0; oo < 4; oo++) {
    int o = o0 + tc * 4 + oo;
    float4 r = {acc[0][oo] + bb[oo], acc[1][oo] + bb[oo], acc[2][oo] + bb[oo], acc[3][oo] + bb[oo]};
    st4(&out[outBase + (size_t)o * HW_ + tp * 4], r);
  }
}

// ------------------------------------------------------------------------------
extern "C" void kernel_launch(void* const* d_in, const int* in_sizes, int n_in,
                              void* d_out, int out_size, void* d_ws, size_t ws_size,
                              hipStream_t stream) {
  const float* x_left  = (const float*)d_in[0];
  const float* x_right = (const float*)d_in[1];
  const float* rb_w1   = (const float*)d_in[2];
  const float* rb_w2   = (const float*)d_in[3];
  const float* b1_w    = (const float*)d_in[4];
  const float* b1_b    = (const float*)d_in[5];
  const float* b2_w    = (const float*)d_in[6];
  const float* b2_b    = (const float*)d_in[7];
  const float* bn_w    = (const float*)d_in[8];
  const float* bn_b    = (const float*)d_in[9];

  float* ws = (float*)d_ws;
  float* R1 = ws;
  float* R2 = ws + (size_t)SIMG;
  float* R3 = ws + (size_t)2 * SIMG;
  float* stats = ws + (size_t)3 * SIMG;              // 4 * P_
  float* rmax = stats;
  float* rsinv = stats + P_;
  float* cmax = stats + 2 * (size_t)P_;
  float* csinv = stats + 3 * (size_t)P_;
  float* colsum = stats + 4 * (size_t)P_;            // [cs_l2r | cs_r2l]
  unsigned int* cnt = (unsigned int*)(colsum + 2 * (size_t)P_);   // 16*25600 u32
  float* V = (float*)(cnt + 409600);                 // [V_l2r | V_r2l]
  float* wT = V + 2 * (size_t)P_;
  float* rbw1T = wT;
  float* rbw2T = wT + 589824;
  float* b1T = wT + 2 * 589824;
  float* b2T = b1T + 65536;
  float* bnT = b2T + 65536;
  size_t need = ((size_t)3 * SIMG + 4 * P_ + 2 * P_ + 409600 + 2 * P_ +
                 2 * 589824 + 2 * 65536 + 131328) * sizeof(float);
  if (ws_size < need) return;                        // clean fail if ws too small

  float* outf = (float*)d_out;
  float* Ml2r = outf;                                // d_out tail doubles as scratch:
  float* scoreM = outf + (size_t)SSCORE;             // score, then M_r2l in-place

  hipMemsetAsync((void*)colsum, 0, (size_t)(2 * P_ + 409600) * 4, stream);

  transpose_rbw_kernel<<<2304, 256, 0, stream>>>(rb_w1, rbw1T);
  transpose_rbw_kernel<<<2304, 256, 0, stream>>>(rb_w2, rbw2T);
  transpose_mat_kernel<<<256, 256, 0, stream>>>(b1_w, b1T, 256);
  transpose_mat_kernel<<<256, 256, 0, stream>>>(b2_w, b2T, 256);
  transpose_mat_kernel<<<513, 256, 0, stream>>>(bn_w, bnT, 513);

  conv3x3_kernel<<<12800, 256, 0, stream>>>(x_left, rbw1T, nullptr, R1, 0);   // silu(conv)
  conv3x3_kernel<<<12800, 256, 0, stream>>>(R1, rbw2T, x_left, R2, 1);        // bl
  conv3x3_kernel<<<12800, 256, 0, stream>>>(x_right, rbw1T, nullptr, R1, 0);
  conv3x3_kernel<<<12800, 256, 0, stream>>>(R1, rbw2T, x_right, R3, 1);       // br

  conv1x1_kernel<<<12800, 256, 0, stream>>>(R2, b1T, b1_b, R1);               // Q (pix-major)
  conv1x1_kernel<<<12800, 256, 0, stream>>>(R3, b2T, b2_b, R2);               // S (pix-major)

  score_kernel<<<11520, 256, 0, stream>>>(R1, R2, scoreM);
  stats_kernel<<<1280, 256, 0, stream>>>(scoreM, rmax, rsinv, cmax, csinv);
  smwrite_kernel<<<11520, 256, 0, stream>>>(scoreM, Ml2r, rmax, rsinv, cmax, csinv,
                                            colsum, colsum + P_);
  morph_kernel<<<16, 1024, 0, stream>>>(colsum, V, cnt);

  buf_kernel<<<15360, 256, 0, stream>>>(scoreM, x_right, R1);                 // buf_l
  buf_kernel<<<15360, 256, 0, stream>>>(Ml2r, x_left, R2);                    // buf_r

  final_kernel<<<12800, 256, 0, stream>>>(R1, x_left, V, bnT, bn_b, outf, 0);
  final_kernel<<<12800, 256, 0, stream>>>(R2, x_right, V + P_, bnT, bn_b, outf, 1);
}